// Round 1
// baseline (8502.302 us; speedup 1.0000x reference)
//
#include <hip/hip_runtime.h>

typedef unsigned short u16;
typedef float f32x4 __attribute__((ext_vector_type(4)));
typedef __bf16 bf16x8 __attribute__((ext_vector_type(8)));

#define NN   4096
#define DD   256
#define NLVL 6
#define LDK  72   // padded LDS k-stride (elements)

static __device__ __forceinline__ u16 f2bf(float f) {
    unsigned int u = __float_as_uint(f);
    u += 0x7fffu + ((u >> 16) & 1u);
    return (u16)(u >> 16);
}
static __device__ __forceinline__ float sigm(float x) { return 1.0f / (1.0f + __expf(-x)); }
static __device__ __forceinline__ float tanh_(float x) { return 2.0f / (1.0f + __expf(-2.0f * x)) - 1.0f; }

// ---------------- weight packing (once per launch) ----------------
// WcombT[chain][C][k] : C = 4*j + ig (gate-interleaved), k<256 -> K[k][ig*256+j], else R[k-256][..]
__global__ void pack_wcomb(const float* __restrict__ kf, const float* __restrict__ rf,
                           const float* __restrict__ kb, const float* __restrict__ rb,
                           const float* __restrict__ bfw, const float* __restrict__ bbw,
                           u16* __restrict__ WcombT, float* __restrict__ biasP) {
    int C = blockIdx.x, chain = blockIdx.y;
    int g = chain >> 1, dir = chain & 1;
    int ig = C & 3, j = C >> 2;
    int oc = ig * 256 + j;
    const float* Ks = (dir ? kb : kf) + g * (256 * 1024);
    const float* Rs = (dir ? rb : rf) + g * (256 * 1024);
    u16* dst = WcombT + (chain * 1024 + C) * 512;
    for (int it = 0; it < 2; ++it) {
        int k = it * 256 + threadIdx.x;
        float v = (k < 256) ? Ks[k * 1024 + oc] : Rs[(k - 256) * 1024 + oc];
        dst[k] = f2bf(v);
    }
    if (threadIdx.x == 0) biasP[chain * 1024 + C] = (dir ? bbw : bfw)[g * 1024 + oc];
}

// fcT[g][n][k] = fc[g][k][n]  (natural column order)
__global__ void pack_fcT(const float* __restrict__ fck, u16* __restrict__ fcT) {
    int n = blockIdx.x, g = blockIdx.y;
    u16* dst = fcT + (g * 256 + n) * 512;
    for (int it = 0; it < 2; ++it) {
        int k = it * 256 + threadIdx.x;
        dst[k] = f2bf(fck[(g * 512 + k) * 256 + n]);
    }
}

// WkT[C][k] = W_kernel[k][C]  (natural order, K=256)
__global__ void pack_wkT(const float* __restrict__ Wk, u16* __restrict__ WkT) {
    int C = blockIdx.x;
    int k = threadIdx.x;
    WkT[C * 256 + k] = f2bf(Wk[k * 1024 + C]);
}

__global__ void convert_x(const float* __restrict__ x, u16* __restrict__ xb) {
    int i = blockIdx.x * 256 + threadIdx.x;
    xb[i] = f2bf(x[i]);
}

// ---------------- per-level prep ----------------
__global__ void gather_children(const int* __restrict__ ind, const u16* __restrict__ h_prev,
                                u16* __restrict__ Hc, int* __restrict__ length) {
    int b = blockIdx.x;
    int k = threadIdx.x >> 5;
    int c0 = (threadIdx.x & 31) * 8;
    int iv = ind[b * 8 + k];
    uint4 v = make_uint4(0u, 0u, 0u, 0u);
    if (iv >= 1) v = *(const uint4*)(h_prev + (iv - 1) * 256 + c0);
    *(uint4*)(Hc + (b * 8 + k) * 256 + c0) = v;
    if (threadIdx.x == 0) {
        int len = 0;
        for (int kk = 0; kk < 8; ++kk) len += (ind[b * 8 + kk] != -1) ? 1 : 0;
        length[b] = len;
    }
}

__global__ void init_states(const float* __restrict__ ihf, const float* __restrict__ icf,
                            const float* __restrict__ ihb, const float* __restrict__ icb,
                            u16* __restrict__ h0, float* __restrict__ cstate) {
    int b = blockIdx.x, chain = blockIdx.y, col = threadIdx.x;
    int g = chain >> 1, dir = chain & 1;
    const float* hs = (dir ? ihb : ihf) + g * 256;
    const float* cs = (dir ? icb : icf) + g * 256;
    int o = (chain * NN + b) * 256 + col;
    h0[o] = f2bf(hs[col]);
    cstate[o] = cs[col];
}

// ---------------- fused recurrent GEMM + LSTM cell ----------------
// grid (32 row-tiles, 8 col-tiles, 8 chains), 256 threads.
// z[b][C] = [x_t(b); h(b)] @ WcombT[chain]^T + bias ; then cell update fused in epilogue.
__global__ __launch_bounds__(256)
void lstm_step_gemm(const u16* __restrict__ Hc, const u16* __restrict__ h_read,
                    u16* __restrict__ h_write, float* __restrict__ cstate,
                    const u16* __restrict__ WcombT, const float* __restrict__ biasP,
                    const int* __restrict__ length, u16* __restrict__ Y0,
                    u16* __restrict__ ylast, int t) {
    __shared__ u16 As[128 * LDK];
    __shared__ u16 Bs[128 * LDK];
    const int chain = blockIdx.z;
    const int dir = chain & 1;
    const int bm0 = blockIdx.x * 128;
    const int bn0 = blockIdx.y * 128;
    const int tid = threadIdx.x;
    const int l = tid & 63;
    const int wave = tid >> 6;
    const int wrow = (wave >> 1) * 64;
    const int wcol = (wave & 1) * 64;

    const u16* hrd = h_read + chain * (NN * 256);
    const u16* Wc = WcombT + chain * (1024 * 512);

    const u16* srcX[4]; const u16* srcH[4]; const u16* srcB[4];
    u16* dstA[4]; u16* dstB[4];
#pragma unroll
    for (int i = 0; i < 4; ++i) {
        int idx = i * 256 + tid;
        int row = idx >> 3;
        int kE = (idx & 7) * 8;
        int b = bm0 + row;
        int tsel = t;
        if (dir) { int len = length[b]; tsel = (t < len) ? (len - 1 - t) : t; }
        srcX[i] = Hc + (b * 8 + tsel) * 256 + kE;
        srcH[i] = hrd + b * 256 + kE;
        srcB[i] = Wc + (bn0 + row) * 512 + kE;
        dstA[i] = As + row * LDK + kE;
        dstB[i] = Bs + row * LDK + kE;
    }

    f32x4 acc[4][4];
    const f32x4 zz = {0.f, 0.f, 0.f, 0.f};
#pragma unroll
    for (int m = 0; m < 4; ++m)
#pragma unroll
        for (int n = 0; n < 4; ++n) acc[m][n] = zz;

    for (int kk = 0; kk < 512; kk += 64) {
#pragma unroll
        for (int i = 0; i < 4; ++i) {
            const u16* s = (kk < 256) ? (srcX[i] + kk) : (srcH[i] + (kk - 256));
            *(uint4*)dstA[i] = *(const uint4*)s;
            *(uint4*)dstB[i] = *(const uint4*)(srcB[i] + kk);
        }
        __syncthreads();
        const int lro = l & 15;
        const int lk = (l >> 4) * 8;
#pragma unroll
        for (int k2 = 0; k2 < 64; k2 += 32) {
            bf16x8 av[4], bv[4];
#pragma unroll
            for (int m = 0; m < 4; ++m)
                av[m] = *(const bf16x8*)(As + (wrow + m * 16 + lro) * LDK + k2 + lk);
#pragma unroll
            for (int n = 0; n < 4; ++n)
                bv[n] = *(const bf16x8*)(Bs + (wcol + n * 16 + lro) * LDK + k2 + lk);
#pragma unroll
            for (int m = 0; m < 4; ++m)
#pragma unroll
                for (int n = 0; n < 4; ++n)
                    acc[m][n] = __builtin_amdgcn_mfma_f32_16x16x32_bf16(av[m], bv[n], acc[m][n], 0, 0, 0);
        }
        __syncthreads();
    }

    // epilogue: quad lanes hold the 4 interleaved gates of one channel
    const int q = l & 3;
    float* cs = cstate + chain * (NN * 256);
    u16* hw = h_write + chain * (NN * 256);
#pragma unroll
    for (int m = 0; m < 4; ++m) {
#pragma unroll
        for (int n = 0; n < 4; ++n) {
            int Cg = bn0 + wcol + n * 16 + (l & 15);
            float bias = biasP[chain * 1024 + Cg];
#pragma unroll
            for (int r = 0; r < 4; ++r) {
                float v = acc[m][n][r] + bias;
                float v1 = __shfl_xor(v, 1);
                float v2 = __shfl_xor(v, 2);
                float v3 = __shfl_xor(v, 3);
                // gate of vK (K = xor distance) is q^K; select K = q^gate
                float zi = (q == 0) ? v : (q == 1) ? v1 : (q == 2) ? v2 : v3;
                float zf = (q == 1) ? v : (q == 0) ? v1 : (q == 3) ? v2 : v3;
                float zg = (q == 2) ? v : (q == 3) ? v1 : (q == 0) ? v2 : v3;
                float zo = (q == 3) ? v : (q == 2) ? v1 : (q == 1) ? v2 : v3;
                if (q == 0) {
                    int R = bm0 + wrow + m * 16 + (l >> 4) * 4 + r;
                    int j = Cg >> 2;
                    int o = R * 256 + j;
                    float cold = cs[o];
                    float cn = sigm(zf) * cold + sigm(zi) * tanh_(zg);
                    float hn = sigm(zo) * tanh_(cn);
                    cs[o] = cn;
                    hw[o] = f2bf(hn);
                    if (chain < 2) {
                        Y0[(R * 8 + t) * 512 + dir * 256 + j] = f2bf(hn);
                    } else {
                        int lenR = length[R];
                        if (t == lenR - 1)
                            ylast[((chain >> 1) - 1) * (NN * 512) + R * 512 + dir * 256 + j] = f2bf(hn);
                    }
                }
            }
        }
    }
}

// ---------------- generic bf16 GEMM (A[M][K] @ B, B given as BT[N][K]) -> fp32 C ----------------
__global__ __launch_bounds__(256)
void gemm_bf16(const u16* __restrict__ A, long long sAz,
               const u16* __restrict__ BT, long long sBz,
               float* __restrict__ Cm, long long sCz,
               const float* __restrict__ bias, int K) {
    __shared__ u16 As[128 * LDK];
    __shared__ u16 Bs[128 * LDK];
    const int z = blockIdx.z;
    A += z * sAz; BT += z * sBz; Cm += z * sCz;
    const int N = gridDim.y * 128;
    const int bm0 = blockIdx.x * 128;
    const int bn0 = blockIdx.y * 128;
    const int tid = threadIdx.x;
    const int l = tid & 63;
    const int wave = tid >> 6;
    const int wrow = (wave >> 1) * 64;
    const int wcol = (wave & 1) * 64;

    const u16* srcA[4]; const u16* srcB[4]; u16* dstA[4]; u16* dstB[4];
#pragma unroll
    for (int i = 0; i < 4; ++i) {
        int idx = i * 256 + tid;
        int row = idx >> 3;
        int kE = (idx & 7) * 8;
        srcA[i] = A + (long long)(bm0 + row) * K + kE;
        srcB[i] = BT + (long long)(bn0 + row) * K + kE;
        dstA[i] = As + row * LDK + kE;
        dstB[i] = Bs + row * LDK + kE;
    }
    f32x4 acc[4][4];
    const f32x4 zz = {0.f, 0.f, 0.f, 0.f};
#pragma unroll
    for (int m = 0; m < 4; ++m)
#pragma unroll
        for (int n = 0; n < 4; ++n) acc[m][n] = zz;

    for (int kk = 0; kk < K; kk += 64) {
#pragma unroll
        for (int i = 0; i < 4; ++i) {
            *(uint4*)dstA[i] = *(const uint4*)(srcA[i] + kk);
            *(uint4*)dstB[i] = *(const uint4*)(srcB[i] + kk);
        }
        __syncthreads();
        const int lro = l & 15;
        const int lk = (l >> 4) * 8;
#pragma unroll
        for (int k2 = 0; k2 < 64; k2 += 32) {
            bf16x8 av[4], bv[4];
#pragma unroll
            for (int m = 0; m < 4; ++m)
                av[m] = *(const bf16x8*)(As + (wrow + m * 16 + lro) * LDK + k2 + lk);
#pragma unroll
            for (int n = 0; n < 4; ++n)
                bv[n] = *(const bf16x8*)(Bs + (wcol + n * 16 + lro) * LDK + k2 + lk);
#pragma unroll
            for (int m = 0; m < 4; ++m)
#pragma unroll
                for (int n = 0; n < 4; ++n)
                    acc[m][n] = __builtin_amdgcn_mfma_f32_16x16x32_bf16(av[m], bv[n], acc[m][n], 0, 0, 0);
        }
        __syncthreads();
    }
#pragma unroll
    for (int m = 0; m < 4; ++m)
#pragma unroll
        for (int n = 0; n < 4; ++n) {
            int Cg = bn0 + wcol + n * 16 + (l & 15);
            float bv = bias ? bias[Cg] : 0.f;
#pragma unroll
            for (int r = 0; r < 4; ++r) {
                int R = bm0 + wrow + m * 16 + (l >> 4) * 4 + r;
                Cm[(long long)R * N + Cg] = acc[m][n][r] + bv;
            }
        }
}

// ---------------- final per-level combine ----------------
__global__ void combine_level(const float* __restrict__ G0, const float* __restrict__ G13,
                              const float* __restrict__ Wx, const int* __restrict__ ind,
                              const float* __restrict__ cprev,
                              float* __restrict__ outH, float* __restrict__ outC,
                              u16* __restrict__ hnext, float* __restrict__ cnext) {
    int b = blockIdx.x;
    int j = threadIdx.x;
    float wf = Wx[b * 1024 + j];          // split order f,i,u,o
    float wi = Wx[b * 1024 + 256 + j];
    float wu = Wx[b * 1024 + 512 + j];
    float wo = Wx[b * 1024 + 768 + j];
    float bfa = 0.f;
#pragma unroll
    for (int k = 0; k < 8; ++k) {
        int iv = ind[b * 8 + k];
        if (iv == -1) continue;
        float cc = (iv >= 1) ? cprev[(iv - 1) * 256 + j] : 0.f;
        bfa += sigm(wf + G0[(b * 8 + k) * 256 + j]) * cc;
    }
    float bi = sigm(G13[0 * NN * 256 + b * 256 + j] + wi);
    float bu = tanh_(G13[1 * NN * 256 + b * 256 + j] + wu);
    float bo = sigm(G13[2 * NN * 256 + b * 256 + j] + wo);
    float nc = bi * bu + bfa;
    float nh = bo * tanh_(nc);
    outH[b * 256 + j] = nh;
    outC[b * 256 + j] = nc;
    hnext[b * 256 + j] = f2bf(nh);
    cnext[b * 256 + j] = nc;
}

extern "C" void kernel_launch(void* const* d_in, const int* in_sizes, int n_in,
                              void* d_out, int out_size, void* d_ws, size_t ws_size,
                              hipStream_t stream) {
    (void)in_sizes; (void)n_in; (void)out_size; (void)ws_size;
    const float* tensor  = (const float*)d_in[0];
    const int*   indices = (const int*)d_in[1];
    const float* Wk      = (const float*)d_in[2];
    const float* Wb      = (const float*)d_in[3];
    const float* kf      = (const float*)d_in[4];
    const float* rf      = (const float*)d_in[5];
    const float* bfw     = (const float*)d_in[6];
    const float* kb      = (const float*)d_in[7];
    const float* rb      = (const float*)d_in[8];
    const float* bbw     = (const float*)d_in[9];
    const float* ihf     = (const float*)d_in[10];
    const float* icf     = (const float*)d_in[11];
    const float* ihb     = (const float*)d_in[12];
    const float* icb     = (const float*)d_in[13];
    const float* fck     = (const float*)d_in[14];
    float* out = (float*)d_out;

    char* p = (char*)d_ws;
    auto take = [&](size_t bytes) -> char* {
        char* r = p;
        p += (bytes + 255) & ~(size_t)255;
        return r;
    };
    u16*   WcombT    = (u16*)  take(8ull * 1024 * 512 * 2);
    float* biasP     = (float*)take(8ull * 1024 * 4);
    u16*   WkT       = (u16*)  take(1024ull * 256 * 2);
    u16*   fcT       = (u16*)  take(4ull * 256 * 512 * 2);
    u16*   Xbf       = (u16*)  take((size_t)NN * 256 * 2);
    u16*   Hc        = (u16*)  take((size_t)NN * 8 * 256 * 2);
    int*   length    = (int*)  take((size_t)NN * 4);
    u16*   hstate0   = (u16*)  take(8ull * NN * 256 * 2);
    u16*   hstate1   = (u16*)  take(8ull * NN * 256 * 2);
    float* cstate    = (float*)take(8ull * NN * 256 * 4);
    u16*   Y0        = (u16*)  take((size_t)NN * 8 * 512 * 2);
    u16*   ylast     = (u16*)  take(3ull * NN * 512 * 2);
    float* Wx        = (float*)take((size_t)NN * 1024 * 4);
    float* G0        = (float*)take((size_t)NN * 8 * 256 * 4);
    float* G13       = (float*)take(3ull * NN * 256 * 4);
    u16*   hprev[2]  = { (u16*)take((size_t)NN * 256 * 2), (u16*)take((size_t)NN * 256 * 2) };
    float* cprev[2]  = { (float*)take((size_t)NN * 256 * 4), (float*)take((size_t)NN * 256 * 4) };
    u16*   hstate[2] = { hstate0, hstate1 };

    // one-time packing
    pack_wcomb<<<dim3(1024, 8), 256, 0, stream>>>(kf, rf, kb, rb, bfw, bbw, WcombT, biasP);
    pack_fcT<<<dim3(256, 4), 256, 0, stream>>>(fck, fcT);
    pack_wkT<<<dim3(1024), 256, 0, stream>>>(Wk, WkT);

    for (int lvl = 0; lvl < NLVL; ++lvl) {
        const int* ind = indices + (size_t)lvl * NN * 8;
        int cur = lvl & 1, nxt = cur ^ 1;

        convert_x<<<dim3(NN), 256, 0, stream>>>(tensor + (size_t)lvl * NN * 256, Xbf);
        gather_children<<<dim3(NN), 256, 0, stream>>>(ind, hprev[cur], Hc, length);
        init_states<<<dim3(NN, 8), 256, 0, stream>>>(ihf, icf, ihb, icb, hstate[0], cstate);

        // Wx = X @ W_kernel + W_bias   (M=4096, N=1024, K=256)
        gemm_bf16<<<dim3(32, 8, 1), 256, 0, stream>>>(Xbf, 0, WkT, 0, Wx, 0, Wb, 256);

        for (int t = 0; t < 8; ++t) {
            lstm_step_gemm<<<dim3(32, 8, 8), 256, 0, stream>>>(
                Hc, hstate[t & 1], hstate[(t & 1) ^ 1], cstate,
                WcombT, biasP, length, Y0, ylast, t);
        }

        // gate0 fc: [N*8, 512] @ fc0 -> G0   (M=32768, N=256, K=512)
        gemm_bf16<<<dim3(256, 2, 1), 256, 0, stream>>>(Y0, 0, fcT, 0, G0, 0, nullptr, 512);
        // gates 1..3 fc: [N, 512] @ fc[g] -> G13[g-1]   (batched over z)
        gemm_bf16<<<dim3(32, 2, 3), 256, 0, stream>>>(
            ylast, (long long)NN * 512, fcT + 256 * 512, (long long)256 * 512,
            G13, (long long)NN * 256, nullptr, 512);

        combine_level<<<dim3(NN), 256, 0, stream>>>(
            G0, G13, Wx, ind, cprev[cur],
            out + (size_t)lvl * NN * 256,
            out + (size_t)NLVL * NN * 256 + (size_t)lvl * NN * 256,
            hprev[nxt], cprev[nxt]);
    }
}

// Round 2
// 7342.442 us; speedup vs baseline: 1.1580x; 1.1580x over previous
//
#include <hip/hip_runtime.h>

typedef unsigned short u16;
typedef float f32x4 __attribute__((ext_vector_type(4)));
typedef __bf16 bf16x8 __attribute__((ext_vector_type(8)));

#define NN   4096
#define NLVL 6
#define LDK  72   // padded LDS k-stride for generic gemm only

static __device__ __forceinline__ u16 f2bf(float f) {
    unsigned int u = __float_as_uint(f);
    u += 0x7fffu + ((u >> 16) & 1u);
    return (u16)(u >> 16);
}
static __device__ __forceinline__ float sigm(float x) { return 1.0f / (1.0f + __expf(-x)); }
static __device__ __forceinline__ float tanh_(float x) { return 2.0f / (1.0f + __expf(-2.0f * x)) - 1.0f; }

// ---------------- weight packing (once per launch) ----------------
// WcombT[chain][C][k] : C = 4*j + ig (gate-interleaved), k<256 -> K[k][ig*256+j], else R[k-256][..]
__global__ void pack_wcomb(const float* __restrict__ kf, const float* __restrict__ rf,
                           const float* __restrict__ kb, const float* __restrict__ rb,
                           const float* __restrict__ bfw, const float* __restrict__ bbw,
                           u16* __restrict__ WcombT, float* __restrict__ biasP) {
    int C = blockIdx.x, chain = blockIdx.y;
    int g = chain >> 1, dir = chain & 1;
    int ig = C & 3, j = C >> 2;
    int oc = ig * 256 + j;
    const float* Ks = (dir ? kb : kf) + g * (256 * 1024);
    const float* Rs = (dir ? rb : rf) + g * (256 * 1024);
    u16* dst = WcombT + (chain * 1024 + C) * 512;
    for (int it = 0; it < 2; ++it) {
        int k = it * 256 + threadIdx.x;
        float v = (k < 256) ? Ks[k * 1024 + oc] : Rs[(k - 256) * 1024 + oc];
        dst[k] = f2bf(v);
    }
    if (threadIdx.x == 0) biasP[chain * 1024 + C] = (dir ? bbw : bfw)[g * 1024 + oc];
}

// fcT[g][n][k] = fc[g][k][n]
__global__ void pack_fcT(const float* __restrict__ fck, u16* __restrict__ fcT) {
    int n = blockIdx.x, g = blockIdx.y;
    u16* dst = fcT + (g * 256 + n) * 512;
    for (int it = 0; it < 2; ++it) {
        int k = it * 256 + threadIdx.x;
        dst[k] = f2bf(fck[(g * 512 + k) * 256 + n]);
    }
}

// WkT[C][k] = W_kernel[k][C]
__global__ void pack_wkT(const float* __restrict__ Wk, u16* __restrict__ WkT) {
    int C = blockIdx.x;
    int k = threadIdx.x;
    WkT[C * 256 + k] = f2bf(Wk[k * 1024 + C]);
}

// ---------------- length histogram + counting sort (once) ----------------
__global__ void compute_len(const int* __restrict__ indices, int* __restrict__ len_all,
                            int* __restrict__ hist) {
    int lvl = blockIdx.y;
    int b = blockIdx.x * 128 + threadIdx.x;
    const int* ind = indices + ((size_t)lvl * NN + b) * 8;
    int len = 0;
#pragma unroll
    for (int k = 0; k < 8; ++k) len += (ind[k] != -1) ? 1 : 0;
    len_all[lvl * NN + b] = len;
    atomicAdd(&hist[lvl * 8 + (len - 1)], 1);
}

// descending-length counting sort: perm[i] = original node, len_p sorted, Mt[t] = #{len>t}
__global__ void build_perm(const int* __restrict__ len_all, const int* __restrict__ hist,
                           int* __restrict__ perm, int* __restrict__ len_p, int* __restrict__ Mt) {
    int lvl = blockIdx.x;
    __shared__ int off[9];
    __shared__ int cur[9];
    if (threadIdx.x == 0) {
        int s = 0;
        for (int L = 8; L >= 1; --L) { off[L] = s; cur[L] = 0; s += hist[lvl * 8 + L - 1]; }
        for (int t = 0; t < 8; ++t) {
            int m = 0;
            for (int L = t + 1; L <= 8; ++L) m += hist[lvl * 8 + L - 1];
            Mt[lvl * 8 + t] = m;
        }
    }
    __syncthreads();
    for (int b = threadIdx.x; b < NN; b += blockDim.x) {
        int len = len_all[lvl * NN + b];
        int pos = off[len] + atomicAdd(&cur[len], 1);
        perm[lvl * NN + pos] = b;
        len_p[lvl * NN + pos] = len;
    }
}

// ---------------- per-level prep (all in permuted row space) ----------------
__global__ void convert_x(const float* __restrict__ x, const int* __restrict__ perm,
                          u16* __restrict__ xb) {
    int i = blockIdx.x;
    int orig = perm[i];
    xb[i * 256 + threadIdx.x] = f2bf(x[orig * 256 + threadIdx.x]);
}

__global__ void gather_children(const int* __restrict__ ind, const int* __restrict__ perm,
                                const u16* __restrict__ h_prev, u16* __restrict__ Hc) {
    int i = blockIdx.x;
    int orig = perm[i];
    int k = threadIdx.x >> 5;
    int c0 = (threadIdx.x & 31) * 8;
    int iv = ind[orig * 8 + k];
    uint4 v = make_uint4(0u, 0u, 0u, 0u);
    if (iv >= 1) v = *(const uint4*)(h_prev + (iv - 1) * 256 + c0);
    *(uint4*)(Hc + (i * 8 + k) * 256 + c0) = v;
}

// h0 layout [chain][i][j]; c layout cT[chain][j][i] (transposed, matches epilogue access)
__global__ void init_states(const float* __restrict__ ihf, const float* __restrict__ icf,
                            const float* __restrict__ ihb, const float* __restrict__ icb,
                            u16* __restrict__ h0, float* __restrict__ cT) {
    int jb = blockIdx.x;              // 0..255
    int chain = blockIdx.y;
    int g = chain >> 1, dir = chain & 1;
    const float* hs = (dir ? ihb : ihf) + g * 256;
    const float* cs = (dir ? icb : icf) + g * 256;
    u16 hv = f2bf(hs[threadIdx.x]);
#pragma unroll
    for (int r = 0; r < 16; ++r) {
        int i = jb * 16 + r;
        h0[((size_t)chain * NN + i) * 256 + threadIdx.x] = hv;
    }
    float cv = cs[jb];
#pragma unroll
    for (int it = 0; it < 16; ++it)
        cT[((size_t)chain * 256 + jb) * NN + it * 256 + threadIdx.x] = cv;
}

// ---------------- fused recurrent GEMM + LSTM cell (transposed z) ----------------
// z^T[C][batch] = WcombT[chain] @ [x_t; h]^T.  Lane holds acc[..][0..3] = gates i,f,g,o of
// one channel j for one batch col -> cell update with zero shuffles/divergence.
// grid (32 batch-tiles, 8 C-tiles, 8 chains) with early-exit at Mt[t].
__global__ __launch_bounds__(256)
void lstm_step(const u16* __restrict__ Hc, const u16* __restrict__ h_read,
               u16* __restrict__ h_write, float* __restrict__ cT,
               const u16* __restrict__ WcombT, const float* __restrict__ biasP,
               const int* __restrict__ len_p, const int* __restrict__ Mt,
               u16* __restrict__ Y0, u16* __restrict__ ylast, int t) {
    const int Mtv = Mt[t];
    const int bi0 = blockIdx.x * 128;
    if (bi0 >= Mtv) return;               // rows all beyond active count -> skip
    __shared__ u16 As[128 * 64];          // weights tile, XOR-swizzled rows (128B/row)
    __shared__ u16 Bs[128 * 64];          // batch tile
    const int cj0 = blockIdx.y * 128;
    const int chain = blockIdx.z;
    const int dir = chain & 1;
    const int tid = threadIdx.x;
    const int l = tid & 63;
    const int wave = tid >> 6;
    const int wrow = (wave >> 1) * 64;    // C side
    const int wcol = (wave & 1) * 64;     // batch side

    const u16* Wc = WcombT + (size_t)chain * (1024 * 512);
    const u16* hrd = h_read + (size_t)chain * (NN * 256);

    const int row0 = tid >> 3;            // 0..31
    const int kseg = tid & 7;             // 16B segment within 64-elem K tile
    const u16* gA = Wc + (cj0 + row0) * 512 + kseg * 8;
    const u16* gH = hrd + (bi0 + row0) * 256 + kseg * 8;
    int xoff[4];
#pragma unroll
    for (int i = 0; i < 4; ++i) {
        int r = bi0 + row0 + i * 32;
        int lenb = len_p[r];
        int ts = dir ? (lenb - 1 - t) : t;
        ts = (ts < 0) ? 0 : ts;           // inactive rows only; value discarded
        xoff[i] = (r * 8 + ts) * 256 + kseg * 8;
    }
    const int dst0 = row0 * 128 + ((kseg * 16) ^ ((row0 & 7) << 4));
    char* Asc = (char*)As;
    char* Bsc = (char*)Bs;

    f32x4 acc[4][4];
    const f32x4 zz = {0.f, 0.f, 0.f, 0.f};
#pragma unroll
    for (int m = 0; m < 4; ++m)
#pragma unroll
        for (int n = 0; n < 4; ++n) acc[m][n] = zz;

    uint4 ra[4], rb[4];
#pragma unroll
    for (int i = 0; i < 4; ++i) {
        ra[i] = *(const uint4*)(gA + i * (32 * 512));
        rb[i] = *(const uint4*)(Hc + xoff[i]);
    }
    for (int kk = 0; kk < 512; kk += 64) {
        if (kk) __syncthreads();
#pragma unroll
        for (int i = 0; i < 4; ++i) {
            *(uint4*)(Asc + dst0 + i * 4096) = ra[i];
            *(uint4*)(Bsc + dst0 + i * 4096) = rb[i];
        }
        __syncthreads();
        if (kk < 448) {                   // prefetch next K tile during MFMA
            int kn = kk + 64;
#pragma unroll
            for (int i = 0; i < 4; ++i) {
                ra[i] = *(const uint4*)(gA + i * (32 * 512) + kn);
                rb[i] = (kn < 256) ? *(const uint4*)(Hc + xoff[i] + kn)
                                   : *(const uint4*)(gH + i * (32 * 256) + (kn - 256));
            }
        }
        const int lro = l & 15;
        const int lsw = (l & 7) << 4;
        const int kb0 = (l >> 4) * 16;
#pragma unroll
        for (int k2 = 0; k2 < 128; k2 += 64) {     // byte offset of k-slice pair
            bf16x8 av[4], bv[4];
#pragma unroll
            for (int m = 0; m < 4; ++m)
                av[m] = *(const bf16x8*)(Asc + (wrow + m * 16 + lro) * 128 + ((kb0 + k2) ^ lsw));
#pragma unroll
            for (int n = 0; n < 4; ++n)
                bv[n] = *(const bf16x8*)(Bsc + (wcol + n * 16 + lro) * 128 + ((kb0 + k2) ^ lsw));
#pragma unroll
            for (int m = 0; m < 4; ++m)
#pragma unroll
                for (int n = 0; n < 4; ++n)
                    acc[m][n] = __builtin_amdgcn_mfma_f32_16x16x32_bf16(av[m], bv[n], acc[m][n], 0, 0, 0);
        }
    }
    __syncthreads();

    // epilogue: lane holds gates i,f,g,o in acc[m][n][0..3] for channel jj, batch col i
    u16* hbuf = As;                        // reuse As as [128][40] u16 transpose buffer
#pragma unroll
    for (int m = 0; m < 4; ++m) {
        int Crow = cj0 + wrow + m * 16 + (l >> 4) * 4;
        float4 bias = *(const float4*)(biasP + chain * 1024 + Crow);
        int jj = Crow >> 2;
        int jl = jj - (cj0 >> 2);
        float* cbase = cT + ((size_t)chain * 256 + jj) * NN;
#pragma unroll
        for (int n = 0; n < 4; ++n) {
            int bl = wcol + n * 16 + (l & 15);
            int i = bi0 + bl;
            float zi = acc[m][n][0] + bias.x;
            float zf = acc[m][n][1] + bias.y;
            float zg = acc[m][n][2] + bias.z;
            float zo = acc[m][n][3] + bias.w;
            float cold = cbase[i];
            float cn = sigm(zf) * cold + sigm(zi) * tanh_(zg);
            float hn = sigm(zo) * tanh_(cn);
            cbase[i] = cn;
            hbuf[bl * 40 + jl] = f2bf(hn);
        }
    }
    __syncthreads();

    u16* hw = h_write + (size_t)chain * (NN * 256);
#pragma unroll
    for (int it = 0; it < 2; ++it) {
        int idx = it * 256 + tid;
        int il = idx >> 2, q = idx & 3;
        uint4 v = *(const uint4*)(hbuf + il * 40 + q * 8);
        int i = bi0 + il;
        int jb = (cj0 >> 2) + q * 8;
        *(uint4*)(hw + (size_t)i * 256 + jb) = v;
        if (chain < 2) {
            *(uint4*)(Y0 + (size_t)(i * 8 + t) * 512 + dir * 256 + jb) = v;
        } else {
            int lp = len_p[i];
            if (t == lp - 1)
                *(uint4*)(ylast + (size_t)((chain >> 1) - 1) * (NN * 512) + (size_t)i * 512 + dir * 256 + jb) = v;
        }
    }
}

// ---------------- generic bf16 GEMM (A[M][K] @ B, B given as BT[N][K]) -> fp32 C ----------------
__global__ __launch_bounds__(256)
void gemm_bf16(const u16* __restrict__ A, long long sAz,
               const u16* __restrict__ BT, long long sBz,
               float* __restrict__ Cm, long long sCz,
               const float* __restrict__ bias, int K) {
    __shared__ u16 As[128 * LDK];
    __shared__ u16 Bs[128 * LDK];
    const int z = blockIdx.z;
    A += z * sAz; BT += z * sBz; Cm += z * sCz;
    const int N = gridDim.y * 128;
    const int bm0 = blockIdx.x * 128;
    const int bn0 = blockIdx.y * 128;
    const int tid = threadIdx.x;
    const int l = tid & 63;
    const int wave = tid >> 6;
    const int wrow = (wave >> 1) * 64;
    const int wcol = (wave & 1) * 64;

    const u16* srcA[4]; const u16* srcB[4]; u16* dstA[4]; u16* dstB[4];
#pragma unroll
    for (int i = 0; i < 4; ++i) {
        int idx = i * 256 + tid;
        int row = idx >> 3;
        int kE = (idx & 7) * 8;
        srcA[i] = A + (long long)(bm0 + row) * K + kE;
        srcB[i] = BT + (long long)(bn0 + row) * K + kE;
        dstA[i] = As + row * LDK + kE;
        dstB[i] = Bs + row * LDK + kE;
    }
    f32x4 acc[4][4];
    const f32x4 zz = {0.f, 0.f, 0.f, 0.f};
#pragma unroll
    for (int m = 0; m < 4; ++m)
#pragma unroll
        for (int n = 0; n < 4; ++n) acc[m][n] = zz;

    for (int kk = 0; kk < K; kk += 64) {
#pragma unroll
        for (int i = 0; i < 4; ++i) {
            *(uint4*)dstA[i] = *(const uint4*)(srcA[i] + kk);
            *(uint4*)dstB[i] = *(const uint4*)(srcB[i] + kk);
        }
        __syncthreads();
        const int lro = l & 15;
        const int lk = (l >> 4) * 8;
#pragma unroll
        for (int k2 = 0; k2 < 64; k2 += 32) {
            bf16x8 av[4], bv[4];
#pragma unroll
            for (int m = 0; m < 4; ++m)
                av[m] = *(const bf16x8*)(As + (wrow + m * 16 + lro) * LDK + k2 + lk);
#pragma unroll
            for (int n = 0; n < 4; ++n)
                bv[n] = *(const bf16x8*)(Bs + (wcol + n * 16 + lro) * LDK + k2 + lk);
#pragma unroll
            for (int m = 0; m < 4; ++m)
#pragma unroll
                for (int n = 0; n < 4; ++n)
                    acc[m][n] = __builtin_amdgcn_mfma_f32_16x16x32_bf16(av[m], bv[n], acc[m][n], 0, 0, 0);
        }
        __syncthreads();
    }
#pragma unroll
    for (int m = 0; m < 4; ++m)
#pragma unroll
        for (int n = 0; n < 4; ++n) {
            int Cg = bn0 + wcol + n * 16 + (l & 15);
            float bv = bias ? bias[Cg] : 0.f;
#pragma unroll
            for (int r = 0; r < 4; ++r) {
                int R = bm0 + wrow + m * 16 + (l >> 4) * 4 + r;
                Cm[(long long)R * N + Cg] = acc[m][n][r] + bv;
            }
        }
}

// ---------------- final per-level combine (permuted space, scatter to original) ----------------
__global__ void combine_level(const float* __restrict__ G0, const float* __restrict__ G13,
                              const float* __restrict__ Wx, const int* __restrict__ ind,
                              const int* __restrict__ perm, const float* __restrict__ cprev,
                              float* __restrict__ outH, float* __restrict__ outC,
                              u16* __restrict__ hnext, float* __restrict__ cnext) {
    int i = blockIdx.x;
    int orig = perm[i];
    int j = threadIdx.x;
    float wf = Wx[i * 1024 + j];          // split order f,i,u,o
    float wi = Wx[i * 1024 + 256 + j];
    float wu = Wx[i * 1024 + 512 + j];
    float wo = Wx[i * 1024 + 768 + j];
    float bfa = 0.f;
#pragma unroll
    for (int k = 0; k < 8; ++k) {
        int iv = ind[orig * 8 + k];
        if (iv == -1) continue;
        float cc = (iv >= 1) ? cprev[(iv - 1) * 256 + j] : 0.f;
        bfa += sigm(wf + G0[(i * 8 + k) * 256 + j]) * cc;
    }
    float bi = sigm(G13[0 * NN * 256 + i * 256 + j] + wi);
    float bu = tanh_(G13[1 * NN * 256 + i * 256 + j] + wu);
    float bo = sigm(G13[2 * NN * 256 + i * 256 + j] + wo);
    float nc = bi * bu + bfa;
    float nh = bo * tanh_(nc);
    outH[orig * 256 + j] = nh;
    outC[orig * 256 + j] = nc;
    hnext[orig * 256 + j] = f2bf(nh);
    cnext[orig * 256 + j] = nc;
}

extern "C" void kernel_launch(void* const* d_in, const int* in_sizes, int n_in,
                              void* d_out, int out_size, void* d_ws, size_t ws_size,
                              hipStream_t stream) {
    (void)in_sizes; (void)n_in; (void)out_size; (void)ws_size;
    const float* tensor  = (const float*)d_in[0];
    const int*   indices = (const int*)d_in[1];
    const float* Wk      = (const float*)d_in[2];
    const float* Wb      = (const float*)d_in[3];
    const float* kf      = (const float*)d_in[4];
    const float* rf      = (const float*)d_in[5];
    const float* bfw     = (const float*)d_in[6];
    const float* kb      = (const float*)d_in[7];
    const float* rb      = (const float*)d_in[8];
    const float* bbw     = (const float*)d_in[9];
    const float* ihf     = (const float*)d_in[10];
    const float* icf     = (const float*)d_in[11];
    const float* ihb     = (const float*)d_in[12];
    const float* icb     = (const float*)d_in[13];
    const float* fck     = (const float*)d_in[14];
    float* out = (float*)d_out;

    char* p = (char*)d_ws;
    auto take = [&](size_t bytes) -> char* {
        char* r = p;
        p += (bytes + 255) & ~(size_t)255;
        return r;
    };
    u16*   WcombT    = (u16*)  take(8ull * 1024 * 512 * 2);
    float* biasP     = (float*)take(8ull * 1024 * 4);
    u16*   WkT       = (u16*)  take(1024ull * 256 * 2);
    u16*   fcT       = (u16*)  take(4ull * 256 * 512 * 2);
    int*   perm      = (int*)  take((size_t)NLVL * NN * 4);
    int*   len_all   = (int*)  take((size_t)NLVL * NN * 4);
    int*   len_p     = (int*)  take((size_t)NLVL * NN * 4);
    int*   hist      = (int*)  take((size_t)NLVL * 8 * 4);
    int*   Mt        = (int*)  take((size_t)NLVL * 8 * 4);
    u16*   Xbf       = (u16*)  take((size_t)NN * 256 * 2);
    u16*   Hc        = (u16*)  take((size_t)NN * 8 * 256 * 2);
    u16*   hstate0   = (u16*)  take(8ull * NN * 256 * 2);
    u16*   hstate1   = (u16*)  take(8ull * NN * 256 * 2);
    float* cT        = (float*)take(8ull * 256 * NN * 4);
    u16*   Y0        = (u16*)  take((size_t)NN * 8 * 512 * 2);
    u16*   ylast     = (u16*)  take(3ull * NN * 512 * 2);
    float* Wx        = (float*)take((size_t)NN * 1024 * 4);
    float* G0        = (float*)take((size_t)NN * 8 * 256 * 4);
    float* G13       = (float*)take(3ull * NN * 256 * 4);
    u16*   hprev[2]  = { (u16*)take((size_t)NN * 256 * 2), (u16*)take((size_t)NN * 256 * 2) };
    float* cprev[2]  = { (float*)take((size_t)NN * 256 * 4), (float*)take((size_t)NN * 256 * 4) };
    u16*   hstate[2] = { hstate0, hstate1 };

    // one-time packing + length sort
    hipMemsetAsync(hist, 0, (size_t)NLVL * 8 * 4, stream);
    pack_wcomb<<<dim3(1024, 8), 256, 0, stream>>>(kf, rf, kb, rb, bfw, bbw, WcombT, biasP);
    pack_fcT<<<dim3(256, 4), 256, 0, stream>>>(fck, fcT);
    pack_wkT<<<dim3(1024), 256, 0, stream>>>(Wk, WkT);
    compute_len<<<dim3(32, NLVL), 128, 0, stream>>>(indices, len_all, hist);
    build_perm<<<dim3(NLVL), 256, 0, stream>>>(len_all, hist, perm, len_p, Mt);

    for (int lvl = 0; lvl < NLVL; ++lvl) {
        const int* ind = indices + (size_t)lvl * NN * 8;
        const int* permL = perm + (size_t)lvl * NN;
        const int* lenpL = len_p + (size_t)lvl * NN;
        const int* MtL = Mt + (size_t)lvl * 8;
        int cur = lvl & 1, nxt = cur ^ 1;

        convert_x<<<dim3(NN), 256, 0, stream>>>(tensor + (size_t)lvl * NN * 256, permL, Xbf);
        gather_children<<<dim3(NN), 256, 0, stream>>>(ind, permL, hprev[cur], Hc);
        init_states<<<dim3(256, 8), 256, 0, stream>>>(ihf, icf, ihb, icb, hstate[0], cT);

        // Wx = X @ W_kernel + W_bias   (M=4096, N=1024, K=256), permuted rows
        gemm_bf16<<<dim3(32, 8, 1), 256, 0, stream>>>(Xbf, 0, WkT, 0, Wx, 0, Wb, 256);

        for (int t = 0; t < 8; ++t) {
            lstm_step<<<dim3(32, 8, 8), 256, 0, stream>>>(
                Hc, hstate[t & 1], hstate[(t & 1) ^ 1], cT,
                WcombT, biasP, lenpL, MtL, Y0, ylast, t);
        }

        // gate0 fc: [N*8, 512] @ fc0 -> G0   (M=32768, N=256, K=512)
        gemm_bf16<<<dim3(256, 2, 1), 256, 0, stream>>>(Y0, 0, fcT, 0, G0, 0, nullptr, 512);
        // gates 1..3 fc: [N, 512] @ fc[g] -> G13[g-1]   (batched over z)
        gemm_bf16<<<dim3(32, 2, 3), 256, 0, stream>>>(
            ylast, (long long)NN * 512, fcT + 256 * 512, (long long)256 * 512,
            G13, (long long)NN * 256, nullptr, 512);

        combine_level<<<dim3(NN), 256, 0, stream>>>(
            G0, G13, Wx, ind, permL, cprev[cur],
            out + (size_t)lvl * NN * 256,
            out + (size_t)NLVL * NN * 256 + (size_t)lvl * NN * 256,
            hprev[nxt], cprev[nxt]);
    }
}

// Round 3
// 5079.775 us; speedup vs baseline: 1.6738x; 1.4454x over previous
//
#include <hip/hip_runtime.h>

typedef unsigned short u16;
typedef float f32x4 __attribute__((ext_vector_type(4)));
typedef __bf16 bf16x8 __attribute__((ext_vector_type(8)));

#define NN   4096
#define NLVL 6
#define LDK  72   // padded LDS k-stride for generic gemm only

static __device__ __forceinline__ u16 f2bf(float f) {
    unsigned int u = __float_as_uint(f);
    u += 0x7fffu + ((u >> 16) & 1u);
    return (u16)(u >> 16);
}
static __device__ __forceinline__ float bf2f(u16 v) {
    return __uint_as_float(((unsigned int)v) << 16);
}
static __device__ __forceinline__ float sigm(float x) { return 1.0f / (1.0f + __expf(-x)); }
static __device__ __forceinline__ float tanh_(float x) { return 2.0f / (1.0f + __expf(-2.0f * x)) - 1.0f; }

// ---------------- weight packing (once per launch) ----------------
// WcombT[chain][C][k] : C = 4*j + ig (gate-interleaved), k<256 -> K[k][ig*256+j], else R[k-256][..]
__global__ void pack_wcomb(const float* __restrict__ kf, const float* __restrict__ rf,
                           const float* __restrict__ kb, const float* __restrict__ rb,
                           const float* __restrict__ bfw, const float* __restrict__ bbw,
                           u16* __restrict__ WcombT, float* __restrict__ biasP) {
    int C = blockIdx.x, chain = blockIdx.y;
    int g = chain >> 1, dir = chain & 1;
    int ig = C & 3, j = C >> 2;
    int oc = ig * 256 + j;
    const float* Ks = (dir ? kb : kf) + g * (256 * 1024);
    const float* Rs = (dir ? rb : rf) + g * (256 * 1024);
    u16* dst = WcombT + (chain * 1024 + C) * 512;
    for (int it = 0; it < 2; ++it) {
        int k = it * 256 + threadIdx.x;
        float v = (k < 256) ? Ks[k * 1024 + oc] : Rs[(k - 256) * 1024 + oc];
        dst[k] = f2bf(v);
    }
    if (threadIdx.x == 0) biasP[chain * 1024 + C] = (dir ? bbw : bfw)[g * 1024 + oc];
}

// fcT[g][n][k] = fc[g][k][n]
__global__ void pack_fcT(const float* __restrict__ fck, u16* __restrict__ fcT) {
    int n = blockIdx.x, g = blockIdx.y;
    u16* dst = fcT + (g * 256 + n) * 512;
    for (int it = 0; it < 2; ++it) {
        int k = it * 256 + threadIdx.x;
        dst[k] = f2bf(fck[(g * 512 + k) * 256 + n]);
    }
}

// WkT[C][k] = W_kernel[k][C]
__global__ void pack_wkT(const float* __restrict__ Wk, u16* __restrict__ WkT) {
    int C = blockIdx.x;
    int k = threadIdx.x;
    WkT[C * 256 + k] = f2bf(Wk[k * 1024 + C]);
}

// h0c[chain][256] bf16, c0c[chain][256] f32 broadcast-init vectors
__global__ void pack_init(const float* __restrict__ ihf, const float* __restrict__ icf,
                          const float* __restrict__ ihb, const float* __restrict__ icb,
                          u16* __restrict__ h0c, float* __restrict__ c0c) {
    int chain = blockIdx.x, j = threadIdx.x;
    int g = chain >> 1, dir = chain & 1;
    h0c[chain * 256 + j] = f2bf((dir ? ihb : ihf)[g * 256 + j]);
    c0c[chain * 256 + j] = (dir ? icb : icf)[g * 256 + j];
}

// ---------------- length histogram + counting sort (once) ----------------
__global__ void compute_len(const int* __restrict__ indices, int* __restrict__ len_all,
                            int* __restrict__ hist) {
    int lvl = blockIdx.y;
    int b = blockIdx.x * 128 + threadIdx.x;
    const int* ind = indices + ((size_t)lvl * NN + b) * 8;
    int len = 0;
#pragma unroll
    for (int k = 0; k < 8; ++k) len += (ind[k] != -1) ? 1 : 0;
    len_all[lvl * NN + b] = len;
    atomicAdd(&hist[lvl * 8 + (len - 1)], 1);
}

// descending-length counting sort: perm[i] = original node, len_p sorted, Mt[t] = #{len>t}
__global__ void build_perm(const int* __restrict__ len_all, const int* __restrict__ hist,
                           int* __restrict__ perm, int* __restrict__ len_p, int* __restrict__ Mt) {
    int lvl = blockIdx.x;
    __shared__ int off[9];
    __shared__ int cur[9];
    if (threadIdx.x == 0) {
        int s = 0;
        for (int L = 8; L >= 1; --L) { off[L] = s; cur[L] = 0; s += hist[lvl * 8 + L - 1]; }
        for (int t = 0; t < 8; ++t) {
            int m = 0;
            for (int L = t + 1; L <= 8; ++L) m += hist[lvl * 8 + L - 1];
            Mt[lvl * 8 + t] = m;
        }
    }
    __syncthreads();
    for (int b = threadIdx.x; b < NN; b += blockDim.x) {
        int len = len_all[lvl * NN + b];
        int pos = off[len] + atomicAdd(&cur[len], 1);
        perm[lvl * NN + pos] = b;
        len_p[lvl * NN + pos] = len;
    }
}

// ---------------- per-level prep (all in permuted row space) ----------------
__global__ void convert_x(const float* __restrict__ x, const int* __restrict__ perm,
                          u16* __restrict__ xb) {
    int i = blockIdx.x;
    int orig = perm[i];
    xb[i * 256 + threadIdx.x] = f2bf(x[orig * 256 + threadIdx.x]);
}

__global__ void gather_children(const int* __restrict__ ind, const int* __restrict__ perm,
                                const u16* __restrict__ h_prev, u16* __restrict__ Hc) {
    int i = blockIdx.x;
    int orig = perm[i];
    int k = threadIdx.x >> 5;
    int c0 = (threadIdx.x & 31) * 8;
    int iv = ind[orig * 8 + k];
    uint4 v = make_uint4(0u, 0u, 0u, 0u);
    if (iv >= 1) v = *(const uint4*)(h_prev + (iv - 1) * 256 + c0);
    *(uint4*)(Hc + (i * 8 + k) * 256 + c0) = v;
}

// ---------------- fused recurrent GEMM + LSTM cell (transposed z) ----------------
// z^T[C][batch] = WcombT[chain] @ [x_t; h]^T.  Lane holds acc[..][0..3] = gates i,f,g,o of
// one channel j for one batch col -> cell update with zero shuffles/divergence.
// 1-D grid 2048, chain = bid&7 (XCD pinning: each XCD touches one chain's weights).
// t==0: h-input/c-input broadcast from h0c/c0c (no init pass, no state read).
__global__ __launch_bounds__(256)
void lstm_step(const u16* __restrict__ Hc, const u16* __restrict__ h_read,
               u16* __restrict__ h_write, float* __restrict__ cT,
               const u16* __restrict__ WcombT, const float* __restrict__ biasP,
               const u16* __restrict__ h0c, const float* __restrict__ c0c,
               const int* __restrict__ len_p, const int* __restrict__ Mt,
               u16* __restrict__ Y0, u16* __restrict__ ylast, int t) {
    const int bid = blockIdx.x;
    const int chain = bid & 7;
    const int rest = bid >> 3;
    const int bi0 = (rest & 31) * 128;
    const int cj0 = (rest >> 5) * 128;
    const int Mtv = Mt[t];
    if (bi0 >= Mtv) return;               // rows all beyond active count -> skip
    __shared__ u16 As[128 * 64];          // weights tile, XOR-swizzled rows (128B/row)
    __shared__ u16 Bs[128 * 64];          // batch tile
    const int dir = chain & 1;
    const int tid = threadIdx.x;
    const int l = tid & 63;
    const int wave = tid >> 6;
    const int wrow = (wave >> 1) * 64;    // C side
    const int wcol = (wave & 1) * 64;     // batch side

    const u16* Wc = WcombT + (size_t)chain * (1024 * 512);
    const u16* hrd = h_read + (size_t)chain * (NN * 256);

    const int row0 = tid >> 3;            // 0..31
    const int kseg = tid & 7;             // 16B segment within 64-elem K tile
    const u16* gA = Wc + (cj0 + row0) * 512 + kseg * 8;
    const u16* gH = hrd + (bi0 + row0) * 256 + kseg * 8;
    const u16* h0b = h0c + chain * 256 + kseg * 8;
    int xoff[4];
#pragma unroll
    for (int i = 0; i < 4; ++i) {
        int r = bi0 + row0 + i * 32;
        int lenb = len_p[r];
        int ts = dir ? (lenb - 1 - t) : t;
        ts = (ts < 0) ? 0 : ts;           // inactive rows only; value discarded
        xoff[i] = (r * 8 + ts) * 256 + kseg * 8;
    }
    const int dst0 = row0 * 128 + ((kseg * 16) ^ ((row0 & 7) << 4));
    char* Asc = (char*)As;
    char* Bsc = (char*)Bs;

    f32x4 acc[4][4];
    const f32x4 zz = {0.f, 0.f, 0.f, 0.f};
#pragma unroll
    for (int m = 0; m < 4; ++m)
#pragma unroll
        for (int n = 0; n < 4; ++n) acc[m][n] = zz;

    uint4 ra[4], rb[4];
#pragma unroll
    for (int i = 0; i < 4; ++i) {
        ra[i] = *(const uint4*)(gA + i * (32 * 512));
        rb[i] = *(const uint4*)(Hc + xoff[i]);
    }
    for (int kk = 0; kk < 512; kk += 64) {
        if (kk) __syncthreads();
#pragma unroll
        for (int i = 0; i < 4; ++i) {
            *(uint4*)(Asc + dst0 + i * 4096) = ra[i];
            *(uint4*)(Bsc + dst0 + i * 4096) = rb[i];
        }
        __syncthreads();
        if (kk < 448) {                   // prefetch next K tile during MFMA
            int kn = kk + 64;
#pragma unroll
            for (int i = 0; i < 4; ++i) {
                ra[i] = *(const uint4*)(gA + i * (32 * 512) + kn);
                rb[i] = (kn < 256) ? *(const uint4*)(Hc + xoff[i] + kn)
                                   : (t ? *(const uint4*)(gH + i * (32 * 256) + (kn - 256))
                                        : *(const uint4*)(h0b + (kn - 256)));
            }
        }
        const int lro = l & 15;
        const int lsw = (l & 7) << 4;
        const int kb0 = (l >> 4) * 16;
#pragma unroll
        for (int k2 = 0; k2 < 128; k2 += 64) {     // byte offset of k-slice pair
            bf16x8 av[4], bv[4];
#pragma unroll
            for (int m = 0; m < 4; ++m)
                av[m] = *(const bf16x8*)(Asc + (wrow + m * 16 + lro) * 128 + ((kb0 + k2) ^ lsw));
#pragma unroll
            for (int n = 0; n < 4; ++n)
                bv[n] = *(const bf16x8*)(Bsc + (wcol + n * 16 + lro) * 128 + ((kb0 + k2) ^ lsw));
#pragma unroll
            for (int m = 0; m < 4; ++m)
#pragma unroll
                for (int n = 0; n < 4; ++n)
                    acc[m][n] = __builtin_amdgcn_mfma_f32_16x16x32_bf16(av[m], bv[n], acc[m][n], 0, 0, 0);
        }
    }
    __syncthreads();

    // epilogue: lane holds gates i,f,g,o in acc[m][n][0..3] for channel jj, batch col i
    const float* c0base = c0c + chain * 256;
    u16* hbuf = As;                        // reuse As as [128][40] u16 transpose buffer
#pragma unroll
    for (int m = 0; m < 4; ++m) {
        int Crow = cj0 + wrow + m * 16 + (l >> 4) * 4;
        float4 bias = *(const float4*)(biasP + chain * 1024 + Crow);
        int jj = Crow >> 2;
        int jl = jj - (cj0 >> 2);
        float* cbase = cT + ((size_t)chain * 256 + jj) * NN;
#pragma unroll
        for (int n = 0; n < 4; ++n) {
            int bl = wcol + n * 16 + (l & 15);
            int i = bi0 + bl;
            float zi = acc[m][n][0] + bias.x;
            float zf = acc[m][n][1] + bias.y;
            float zg = acc[m][n][2] + bias.z;
            float zo = acc[m][n][3] + bias.w;
            float cold = t ? cbase[i] : c0base[jj];
            float cn = sigm(zf) * cold + sigm(zi) * tanh_(zg);
            float hn = sigm(zo) * tanh_(cn);
            cbase[i] = cn;
            hbuf[bl * 40 + jl] = f2bf(hn);
        }
    }
    __syncthreads();

    u16* hw = h_write + (size_t)chain * (NN * 256);
#pragma unroll
    for (int it = 0; it < 2; ++it) {
        int idx = it * 256 + tid;
        int il = idx >> 2, q = idx & 3;
        uint4 v = *(const uint4*)(hbuf + il * 40 + q * 8);
        int i = bi0 + il;
        int jb = (cj0 >> 2) + q * 8;
        *(uint4*)(hw + (size_t)i * 256 + jb) = v;
        if (chain < 2) {
            *(uint4*)(Y0 + (size_t)(i * 8 + t) * 512 + dir * 256 + jb) = v;
        } else {
            int lp = len_p[i];
            if (t == lp - 1)
                *(uint4*)(ylast + (size_t)((chain >> 1) - 1) * (NN * 512) + (size_t)i * 512 + dir * 256 + jb) = v;
        }
    }
}

// ---------------- generic bf16 GEMM (A[M][K] @ BT[N][K]) -> f32 or bf16 C ----------------
__global__ __launch_bounds__(256)
void gemm_bf16(const u16* __restrict__ A, long long sAz,
               const u16* __restrict__ BT, long long sBz,
               void* __restrict__ Craw, long long sCz,
               const float* __restrict__ bias, int K, int obf) {
    __shared__ u16 As[128 * LDK];
    __shared__ u16 Bs[128 * LDK];
    const int z = blockIdx.z;
    A += z * sAz; BT += z * sBz;
    const int N = gridDim.y * 128;
    const int bm0 = blockIdx.x * 128;
    const int bn0 = blockIdx.y * 128;
    const int tid = threadIdx.x;
    const int l = tid & 63;
    const int wave = tid >> 6;
    const int wrow = (wave >> 1) * 64;
    const int wcol = (wave & 1) * 64;

    const u16* srcA[4]; const u16* srcB[4]; u16* dstA[4]; u16* dstB[4];
#pragma unroll
    for (int i = 0; i < 4; ++i) {
        int idx = i * 256 + tid;
        int row = idx >> 3;
        int kE = (idx & 7) * 8;
        srcA[i] = A + (long long)(bm0 + row) * K + kE;
        srcB[i] = BT + (long long)(bn0 + row) * K + kE;
        dstA[i] = As + row * LDK + kE;
        dstB[i] = Bs + row * LDK + kE;
    }
    f32x4 acc[4][4];
    const f32x4 zz = {0.f, 0.f, 0.f, 0.f};
#pragma unroll
    for (int m = 0; m < 4; ++m)
#pragma unroll
        for (int n = 0; n < 4; ++n) acc[m][n] = zz;

    for (int kk = 0; kk < K; kk += 64) {
#pragma unroll
        for (int i = 0; i < 4; ++i) {
            *(uint4*)dstA[i] = *(const uint4*)(srcA[i] + kk);
            *(uint4*)dstB[i] = *(const uint4*)(srcB[i] + kk);
        }
        __syncthreads();
        const int lro = l & 15;
        const int lk = (l >> 4) * 8;
#pragma unroll
        for (int k2 = 0; k2 < 64; k2 += 32) {
            bf16x8 av[4], bv[4];
#pragma unroll
            for (int m = 0; m < 4; ++m)
                av[m] = *(const bf16x8*)(As + (wrow + m * 16 + lro) * LDK + k2 + lk);
#pragma unroll
            for (int n = 0; n < 4; ++n)
                bv[n] = *(const bf16x8*)(Bs + (wcol + n * 16 + lro) * LDK + k2 + lk);
#pragma unroll
            for (int m = 0; m < 4; ++m)
#pragma unroll
                for (int n = 0; n < 4; ++n)
                    acc[m][n] = __builtin_amdgcn_mfma_f32_16x16x32_bf16(av[m], bv[n], acc[m][n], 0, 0, 0);
        }
        __syncthreads();
    }
#pragma unroll
    for (int m = 0; m < 4; ++m)
#pragma unroll
        for (int n = 0; n < 4; ++n) {
            int Cg = bn0 + wcol + n * 16 + (l & 15);
            float bv = bias ? bias[Cg] : 0.f;
#pragma unroll
            for (int r = 0; r < 4; ++r) {
                int R = bm0 + wrow + m * 16 + (l >> 4) * 4 + r;
                float v = acc[m][n][r] + bv;
                if (obf) ((u16*)Craw)[z * sCz + (long long)R * N + Cg] = f2bf(v);
                else     ((float*)Craw)[z * sCz + (long long)R * N + Cg] = v;
            }
        }
}

// ---------------- final per-level combine (permuted space, scatter to original) ----------------
__global__ void combine_level(const u16* __restrict__ G0, const u16* __restrict__ G13,
                              const u16* __restrict__ Wx, const int* __restrict__ ind,
                              const int* __restrict__ perm, const float* __restrict__ cprev,
                              float* __restrict__ outH, float* __restrict__ outC,
                              u16* __restrict__ hnext, float* __restrict__ cnext) {
    int i = blockIdx.x;
    int orig = perm[i];
    int j = threadIdx.x;
    float wf = bf2f(Wx[i * 1024 + j]);          // split order f,i,u,o
    float wi = bf2f(Wx[i * 1024 + 256 + j]);
    float wu = bf2f(Wx[i * 1024 + 512 + j]);
    float wo = bf2f(Wx[i * 1024 + 768 + j]);
    float bfa = 0.f;
#pragma unroll
    for (int k = 0; k < 8; ++k) {
        int iv = ind[orig * 8 + k];
        if (iv == -1) continue;
        float cc = (iv >= 1) ? cprev[(iv - 1) * 256 + j] : 0.f;
        bfa += sigm(wf + bf2f(G0[(i * 8 + k) * 256 + j])) * cc;
    }
    float bi = sigm(bf2f(G13[0 * NN * 256 + i * 256 + j]) + wi);
    float bu = tanh_(bf2f(G13[1 * NN * 256 + i * 256 + j]) + wu);
    float bo = sigm(bf2f(G13[2 * NN * 256 + i * 256 + j]) + wo);
    float nc = bi * bu + bfa;
    float nh = bo * tanh_(nc);
    outH[orig * 256 + j] = nh;
    outC[orig * 256 + j] = nc;
    hnext[orig * 256 + j] = f2bf(nh);
    cnext[orig * 256 + j] = nc;
}

extern "C" void kernel_launch(void* const* d_in, const int* in_sizes, int n_in,
                              void* d_out, int out_size, void* d_ws, size_t ws_size,
                              hipStream_t stream) {
    (void)in_sizes; (void)n_in; (void)out_size; (void)ws_size;
    const float* tensor  = (const float*)d_in[0];
    const int*   indices = (const int*)d_in[1];
    const float* Wk      = (const float*)d_in[2];
    const float* Wb      = (const float*)d_in[3];
    const float* kf      = (const float*)d_in[4];
    const float* rf      = (const float*)d_in[5];
    const float* bfw     = (const float*)d_in[6];
    const float* kb      = (const float*)d_in[7];
    const float* rb      = (const float*)d_in[8];
    const float* bbw     = (const float*)d_in[9];
    const float* ihf     = (const float*)d_in[10];
    const float* icf     = (const float*)d_in[11];
    const float* ihb     = (const float*)d_in[12];
    const float* icb     = (const float*)d_in[13];
    const float* fck     = (const float*)d_in[14];
    float* out = (float*)d_out;

    char* p = (char*)d_ws;
    auto take = [&](size_t bytes) -> char* {
        char* r = p;
        p += (bytes + 255) & ~(size_t)255;
        return r;
    };
    u16*   WcombT    = (u16*)  take(8ull * 1024 * 512 * 2);
    float* biasP     = (float*)take(8ull * 1024 * 4);
    u16*   WkT       = (u16*)  take(1024ull * 256 * 2);
    u16*   fcT       = (u16*)  take(4ull * 256 * 512 * 2);
    u16*   h0c       = (u16*)  take(8ull * 256 * 2);
    float* c0c       = (float*)take(8ull * 256 * 4);
    int*   perm      = (int*)  take((size_t)NLVL * NN * 4);
    int*   len_all   = (int*)  take((size_t)NLVL * NN * 4);
    int*   len_p     = (int*)  take((size_t)NLVL * NN * 4);
    int*   hist      = (int*)  take((size_t)NLVL * 8 * 4);
    int*   Mt        = (int*)  take((size_t)NLVL * 8 * 4);
    u16*   Xbf       = (u16*)  take((size_t)NN * 256 * 2);
    u16*   Hc        = (u16*)  take((size_t)NN * 8 * 256 * 2);
    u16*   hstate0   = (u16*)  take(8ull * NN * 256 * 2);
    u16*   hstate1   = (u16*)  take(8ull * NN * 256 * 2);
    float* cT        = (float*)take(8ull * 256 * NN * 4);
    u16*   Y0        = (u16*)  take((size_t)NN * 8 * 512 * 2);
    u16*   ylast     = (u16*)  take(3ull * NN * 512 * 2);
    u16*   Wx        = (u16*)  take((size_t)NN * 1024 * 2);
    u16*   G0        = (u16*)  take((size_t)NN * 8 * 256 * 2);
    u16*   G13       = (u16*)  take(3ull * NN * 256 * 2);
    u16*   hprev[2]  = { (u16*)take((size_t)NN * 256 * 2), (u16*)take((size_t)NN * 256 * 2) };
    float* cprev[2]  = { (float*)take((size_t)NN * 256 * 4), (float*)take((size_t)NN * 256 * 4) };
    u16*   hstate[2] = { hstate0, hstate1 };

    // one-time packing + length sort
    hipMemsetAsync(hist, 0, (size_t)NLVL * 8 * 4, stream);
    pack_wcomb<<<dim3(1024, 8), 256, 0, stream>>>(kf, rf, kb, rb, bfw, bbw, WcombT, biasP);
    pack_fcT<<<dim3(256, 4), 256, 0, stream>>>(fck, fcT);
    pack_wkT<<<dim3(1024), 256, 0, stream>>>(Wk, WkT);
    pack_init<<<dim3(8), 256, 0, stream>>>(ihf, icf, ihb, icb, h0c, c0c);
    compute_len<<<dim3(32, NLVL), 128, 0, stream>>>(indices, len_all, hist);
    build_perm<<<dim3(NLVL), 256, 0, stream>>>(len_all, hist, perm, len_p, Mt);

    for (int lvl = 0; lvl < NLVL; ++lvl) {
        const int* ind = indices + (size_t)lvl * NN * 8;
        const int* permL = perm + (size_t)lvl * NN;
        const int* lenpL = len_p + (size_t)lvl * NN;
        const int* MtL = Mt + (size_t)lvl * 8;
        int cur = lvl & 1, nxt = cur ^ 1;

        convert_x<<<dim3(NN), 256, 0, stream>>>(tensor + (size_t)lvl * NN * 256, permL, Xbf);
        gather_children<<<dim3(NN), 256, 0, stream>>>(ind, permL, hprev[cur], Hc);

        // Wx = X @ W_kernel + W_bias   (M=4096, N=1024, K=256), permuted rows -> bf16
        gemm_bf16<<<dim3(32, 8, 1), 256, 0, stream>>>(Xbf, 0, WkT, 0, Wx, 0, Wb, 256, 1);

        for (int t = 0; t < 8; ++t) {
            lstm_step<<<dim3(2048), 256, 0, stream>>>(
                Hc, hstate[t & 1], hstate[(t & 1) ^ 1], cT,
                WcombT, biasP, h0c, c0c, lenpL, MtL, Y0, ylast, t);
        }

        // gate0 fc: [N*8, 512] @ fc0 -> G0 bf16   (M=32768, N=256, K=512)
        gemm_bf16<<<dim3(256, 2, 1), 256, 0, stream>>>(Y0, 0, fcT, 0, G0, 0, nullptr, 512, 1);
        // gates 1..3 fc: [N, 512] @ fc[g] -> G13[g-1] bf16   (batched over z)
        gemm_bf16<<<dim3(32, 2, 3), 256, 0, stream>>>(
            ylast, (long long)NN * 512, fcT + 256 * 512, (long long)256 * 512,
            G13, (long long)NN * 256, nullptr, 512, 1);

        combine_level<<<dim3(NN), 256, 0, stream>>>(
            G0, G13, Wx, ind, permL, cprev[cur],
            out + (size_t)lvl * NN * 256,
            out + (size_t)NLVL * NN * 256 + (size_t)lvl * NN * 256,
            hprev[nxt], cprev[nxt]);
    }
}